// Round 3
// baseline (782.492 us; speedup 1.0000x reference)
//
#include <hip/hip_runtime.h>
#include <hip/hip_bf16.h>

// GAT layer, B=8 N=4096 F=128 U=64, ALL I/O float32 (per reference dtypes).
// out = relu( softmax_row( lrelu(s_i + t_j) masked by A ) @ X ),  X = H@W,
// s = X@a1, t = X@a2.  Only A is O(N^2): 512 MB f32 -> ~86 us HBM floor.
// Internal: bf16 MFMA for X=H@W and alpha@X; f32 softmax denominator.
// R3 change: nontemporal loads on the A stream (touched exactly once) so the
// reused XT/t tensors stay L2-resident; nontemporal out stores.

#define NTOK 4096
#define FDIM 128
#define UDIM 64
#define BATCH 8

typedef __attribute__((ext_vector_type(8))) short short8;
typedef __attribute__((ext_vector_type(4))) float f32x4;

// round-to-nearest-even f32 -> bf16
__device__ __forceinline__ unsigned short f2bf(float x) {
    unsigned u = __float_as_uint(x);
    return (unsigned short)((u + 0x7fffu + ((u >> 16) & 1u)) >> 16);
}

// ---------------- kernel 1: X = H@W (MFMA), s = X@a1, t = X@a2, XT bf16 ----
// grid 512 blocks x 256 thr; each wave handles a 16-row tile (2048 tiles).
__global__ __launch_bounds__(256) void prep_kernel(
    const float* __restrict__ H,    // f32 [B*N, 128]
    const float* __restrict__ W,    // f32 [128, 64]
    const float* __restrict__ a1,   // f32 [64]
    const float* __restrict__ a2,   // f32 [64]
    unsigned short* __restrict__ XT,// bf16 [B, 64, N] (scratch)
    float* __restrict__ s_out,      // f32 [B*N]
    float* __restrict__ t_out)      // f32 [B*N]
{
    __shared__ float Xl[4][16][UDIM + 1];   // per-wave X tile, padded

    const int tid  = threadIdx.x;
    const int wave = tid >> 6, lane = tid & 63;
    const int col  = lane & 15, quad = lane >> 4;
    const int i0   = (blockIdx.x * 4 + wave) * 16;   // global row base (b*N + n)

    f32x4 acc0 = {0,0,0,0}, acc1 = {0,0,0,0}, acc2 = {0,0,0,0}, acc3 = {0,0,0,0};
    const float* hrow = H + (size_t)(i0 + col) * FDIM + quad * 8;

    #pragma unroll
    for (int kb = 0; kb < FDIM; kb += 32) {
        f32x4 h0 = *(const f32x4*)(hrow + kb);       // A[m=lane&15][k=quad*8+j]
        f32x4 h1 = *(const f32x4*)(hrow + kb + 4);
        short8 afr, b0, b1, b2, b3;
        #pragma unroll
        for (int j = 0; j < 4; ++j) {
            afr[j]     = (short)f2bf(h0[j]);
            afr[4 + j] = (short)f2bf(h1[j]);
        }
        #pragma unroll
        for (int j = 0; j < 8; ++j) {                // B[k][n=lane&15]; W tiny, L1-hot
            int k = kb + quad * 8 + j;
            b0[j] = (short)f2bf(W[k * UDIM + col]);
            b1[j] = (short)f2bf(W[k * UDIM + 16 + col]);
            b2[j] = (short)f2bf(W[k * UDIM + 32 + col]);
            b3[j] = (short)f2bf(W[k * UDIM + 48 + col]);
        }
        acc0 = __builtin_amdgcn_mfma_f32_16x16x32_bf16(afr, b0, acc0, 0, 0, 0);
        acc1 = __builtin_amdgcn_mfma_f32_16x16x32_bf16(afr, b1, acc1, 0, 0, 0);
        acc2 = __builtin_amdgcn_mfma_f32_16x16x32_bf16(afr, b2, acc2, 0, 0, 0);
        acc3 = __builtin_amdgcn_mfma_f32_16x16x32_bf16(afr, b3, acc3, 0, 0, 0);
    }
    // C/D layout: col(u) = lane&15 (+16 per group), row = quad*4 + reg
    #pragma unroll
    for (int r = 0; r < 4; ++r) {
        Xl[wave][quad * 4 + r][col]      = acc0[r];
        Xl[wave][quad * 4 + r][16 + col] = acc1[r];
        Xl[wave][quad * 4 + r][32 + col] = acc2[r];
        Xl[wave][quad * 4 + r][48 + col] = acc3[r];
    }
    __syncthreads();

    const int b = i0 >> 12, n0 = i0 & (NTOK - 1);
    // s,t from f32 X: lane (n=col, u-chunk=quad) partial, then quad-reduce
    float ps = 0.f, pt = 0.f;
    #pragma unroll
    for (int ui = 0; ui < 16; ++ui) {
        int u = quad * 16 + ui;
        float x = Xl[wave][col][u];
        ps = fmaf(x, a1[u], ps);
        pt = fmaf(x, a2[u], pt);
    }
    ps += __shfl_xor(ps, 16, 64); ps += __shfl_xor(ps, 32, 64);
    pt += __shfl_xor(pt, 16, 64); pt += __shfl_xor(pt, 32, 64);
    if (quad == 0) s_out[i0 + col] = ps;
    if (quad == 1) t_out[i0 + col] = pt;

    // XT[b][u][n] bf16 store (transposed so attn B-frags are contiguous loads)
    #pragma unroll
    for (int ui = 0; ui < 16; ++ui) {
        int u = quad * 16 + ui;
        XT[(size_t)(b * UDIM + u) * NTOK + n0 + col] = f2bf(Xl[wave][col][u]);
    }
}

// ---------------- kernel 2: fused mask+softmax+PV ---------------------------
// grid 2048 = 8 batches x 256 row-tiles (b = bx&7: round-robin XCD dispatch
// pins one batch per XCD -> XT[b] 512KB stays L2-hot), 4 waves/block,
// each wave: 16-row tile x K-chunk 1024, K-step 32.
__global__ __launch_bounds__(256) void attn_kernel(
    const float* __restrict__ A,    // f32 [B, N, N] -- the 512 MB stream
    const unsigned short* __restrict__ XT,  // bf16 [B, 64, N]
    const float* __restrict__ s_in,
    const float* __restrict__ t_in,
    float* __restrict__ out)        // f32 [B, N, 64]
{
    __shared__ float part[4][16][UDIM + 1]; // per-wave partial numerators
    __shared__ float denl[4][16];           // per-wave partial denominators

    const int tid  = threadIdx.x;
    const int wave = tid >> 6, lane = tid & 63;
    const int bx   = blockIdx.x;
    const int b    = bx & 7;
    const int i0   = (bx >> 3) * 16;
    const int col  = lane & 15, quad = lane >> 4;
    const int kstart = wave * (NTOK / 4);

    const float s_m = s_in[b * NTOK + i0 + col];   // A-frag row m = lane&15

    const float* aptr = A + ((size_t)(b * NTOK + i0 + col)) * NTOK + kstart + quad * 8;
    const float* tptr = t_in + b * NTOK + kstart + quad * 8;
    const unsigned short* xb  = XT + (size_t)b * UDIM * NTOK + kstart + quad * 8;
    const unsigned short* xp0 = xb + (size_t)(col)      * NTOK;
    const unsigned short* xp1 = xb + (size_t)(16 + col) * NTOK;
    const unsigned short* xp2 = xb + (size_t)(32 + col) * NTOK;
    const unsigned short* xp3 = xb + (size_t)(48 + col) * NTOK;

    f32x4 acc0 = {0,0,0,0}, acc1 = {0,0,0,0}, acc2 = {0,0,0,0}, acc3 = {0,0,0,0};
    float den = 0.f;
    const float LOG2E = 1.44269504f;

    #pragma unroll 2
    for (int step = 0; step < 32; ++step) {
        // A is streamed exactly once -> nontemporal (don't evict XT/t from L2)
        f32x4 am0 = __builtin_nontemporal_load((const f32x4*)aptr);
        f32x4 am1 = __builtin_nontemporal_load((const f32x4*)(aptr + 4));
        f32x4 t0  = *(const f32x4*)tptr;           // t_k fp32 (L2-hot)
        f32x4 t1  = *(const f32x4*)(tptr + 4);
        short8 bf0 = *(const short8*)xp0;          // B-frags (bf16, L2-hot)
        short8 bf1 = *(const short8*)xp1;
        short8 bf2 = *(const short8*)xp2;
        short8 bf3 = *(const short8*)xp3;

        float w[8];
        #pragma unroll
        for (int j = 0; j < 4; ++j) {
            float l0 = s_m + t0[j], l1 = s_m + t1[j];
            float e0 = fmaxf(l0, 0.2f * l0);        // leaky_relu (exact both signs)
            float e1 = fmaxf(l1, 0.2f * l1);
            // no max-shift needed: logits <= ~9 -> exp <= ~1e4, f32-safe;
            // masked entries become exact 0 (matches exp(-1e10) = 0)
            float w0 = __builtin_amdgcn_exp2f(e0 * LOG2E) * am0[j];
            float w1 = __builtin_amdgcn_exp2f(e1 * LOG2E) * am1[j];
            den += w0 + w1;
            w[j] = w0; w[4 + j] = w1;
        }
        short8 afr;
        #pragma unroll
        for (int j = 0; j < 4; ++j) {
            afr[j]     = (short)f2bf(w[j]);         // A-frag k = quad*8 + {0..3}
            afr[4 + j] = (short)f2bf(w[4 + j]);     //           k = quad*8 + {4..7}
        }

        acc0 = __builtin_amdgcn_mfma_f32_16x16x32_bf16(afr, bf0, acc0, 0, 0, 0);
        acc1 = __builtin_amdgcn_mfma_f32_16x16x32_bf16(afr, bf1, acc1, 0, 0, 0);
        acc2 = __builtin_amdgcn_mfma_f32_16x16x32_bf16(afr, bf2, acc2, 0, 0, 0);
        acc3 = __builtin_amdgcn_mfma_f32_16x16x32_bf16(afr, bf3, acc3, 0, 0, 0);

        aptr += 32; tptr += 32; xp0 += 32; xp1 += 32; xp2 += 32; xp3 += 32;
    }

    // denominator: quad-reduce -> lanes with same col hold the row-chunk sum
    den += __shfl_xor(den, 16, 64);
    den += __shfl_xor(den, 32, 64);
    if (quad == 0) denl[wave][col] = den;

    #pragma unroll
    for (int r = 0; r < 4; ++r) {
        part[wave][quad * 4 + r][col]      = acc0[r];
        part[wave][quad * 4 + r][16 + col] = acc1[r];
        part[wave][quad * 4 + r][32 + col] = acc2[r];
        part[wave][quad * 4 + r][48 + col] = acc3[r];
    }
    __syncthreads();

    // cross-wave reduce + divide + relu + f32 store (coalesced over u)
    #pragma unroll
    for (int rep = 0; rep < 4; ++rep) {
        int e = rep * 256 + tid;
        int r = e >> 6, u = e & 63;
        float num = part[0][r][u] + part[1][r][u] + part[2][r][u] + part[3][r][u];
        float dd  = denl[0][r] + denl[1][r] + denl[2][r] + denl[3][r];
        float o   = fmaxf(num / dd, 0.f);
        __builtin_nontemporal_store(o, &out[(size_t)(b * NTOK + i0 + r) * UDIM + u]);
    }
}

extern "C" void kernel_launch(void* const* d_in, const int* in_sizes, int n_in,
                              void* d_out, int out_size, void* d_ws, size_t ws_size,
                              hipStream_t stream) {
    const float* H  = (const float*)d_in[0];
    const float* A  = (const float*)d_in[1];
    const float* W  = (const float*)d_in[2];
    const float* a1 = (const float*)d_in[3];
    const float* a2 = (const float*)d_in[4];
    float* out = (float*)d_out;

    char* ws = (char*)d_ws;
    unsigned short* XT = (unsigned short*)ws;                               // 4 MB bf16
    float* s = (float*)(ws + (size_t)BATCH * UDIM * NTOK * 2);              // 128 KB
    float* t = (float*)(ws + (size_t)BATCH * UDIM * NTOK * 2 + (size_t)BATCH * NTOK * 4);

    prep_kernel<<<512, 256, 0, stream>>>(H, W, a1, a2, XT, s, t);
    attn_kernel<<<2048, 256, 0, stream>>>(A, XT, s, t, out);
}

// Round 4
// 739.893 us; speedup vs baseline: 1.0576x; 1.0576x over previous
//
#include <hip/hip_runtime.h>
#include <hip/hip_bf16.h>

// GAT layer, B=8 N=4096 F=128 U=64, ALL I/O float32.
// out = relu( softmax_row( lrelu(s_i + t_j) masked by A ) @ X ),  X = H@W.
// A is the only O(N^2) tensor: 512 MB f32 -> ~86 us HBM floor.
// R4: 64 rows/block (4 row-groups per wave) so XT/t/B-frag loads are shared
// 4x -> XT aggregate traffic 1 GB -> 256 MB; exp2-domain s,t (LOG2E folded at
// prep); cheap round+v_perm bf16 pack.

#define NTOK 4096
#define FDIM 128
#define UDIM 64
#define BATCH 8

typedef __attribute__((ext_vector_type(8))) short short8;
typedef __attribute__((ext_vector_type(4))) float f32x4;

union PackU { unsigned u[4]; short8 s; };

// round-to-nearest-even f32 -> bf16 (used in prep only)
__device__ __forceinline__ unsigned short f2bf(float x) {
    unsigned u = __float_as_uint(x);
    return (unsigned short)((u + 0x7fffu + ((u >> 16) & 1u)) >> 16);
}

// ---------------- kernel 1: X = H@W (MFMA), s,t (pre-scaled by log2e) ------
__global__ __launch_bounds__(256) void prep_kernel(
    const float* __restrict__ H,    // f32 [B*N, 128]
    const float* __restrict__ W,    // f32 [128, 64]
    const float* __restrict__ a1,   // f32 [64]
    const float* __restrict__ a2,   // f32 [64]
    unsigned short* __restrict__ XT,// bf16 [B, 64, N] (scratch)
    float* __restrict__ s_out,      // f32 [B*N], = (X@a1)*log2(e)
    float* __restrict__ t_out)      // f32 [B*N], = (X@a2)*log2(e)
{
    __shared__ float Xl[4][16][UDIM + 1];

    const int tid  = threadIdx.x;
    const int wave = tid >> 6, lane = tid & 63;
    const int col  = lane & 15, quad = lane >> 4;
    const int i0   = (blockIdx.x * 4 + wave) * 16;

    f32x4 acc0 = {0,0,0,0}, acc1 = {0,0,0,0}, acc2 = {0,0,0,0}, acc3 = {0,0,0,0};
    const float* hrow = H + (size_t)(i0 + col) * FDIM + quad * 8;

    #pragma unroll
    for (int kb = 0; kb < FDIM; kb += 32) {
        f32x4 h0 = *(const f32x4*)(hrow + kb);       // A[m=lane&15][k=quad*8+j]
        f32x4 h1 = *(const f32x4*)(hrow + kb + 4);
        short8 afr, b0, b1, b2, b3;
        #pragma unroll
        for (int j = 0; j < 4; ++j) {
            afr[j]     = (short)f2bf(h0[j]);
            afr[4 + j] = (short)f2bf(h1[j]);
        }
        #pragma unroll
        for (int j = 0; j < 8; ++j) {                // W tiny, L1-hot
            int k = kb + quad * 8 + j;
            b0[j] = (short)f2bf(W[k * UDIM + col]);
            b1[j] = (short)f2bf(W[k * UDIM + 16 + col]);
            b2[j] = (short)f2bf(W[k * UDIM + 32 + col]);
            b3[j] = (short)f2bf(W[k * UDIM + 48 + col]);
        }
        acc0 = __builtin_amdgcn_mfma_f32_16x16x32_bf16(afr, b0, acc0, 0, 0, 0);
        acc1 = __builtin_amdgcn_mfma_f32_16x16x32_bf16(afr, b1, acc1, 0, 0, 0);
        acc2 = __builtin_amdgcn_mfma_f32_16x16x32_bf16(afr, b2, acc2, 0, 0, 0);
        acc3 = __builtin_amdgcn_mfma_f32_16x16x32_bf16(afr, b3, acc3, 0, 0, 0);
    }
    #pragma unroll
    for (int r = 0; r < 4; ++r) {   // C/D: col(u)=lane&15 (+16/group), row=quad*4+r
        Xl[wave][quad * 4 + r][col]      = acc0[r];
        Xl[wave][quad * 4 + r][16 + col] = acc1[r];
        Xl[wave][quad * 4 + r][32 + col] = acc2[r];
        Xl[wave][quad * 4 + r][48 + col] = acc3[r];
    }
    __syncthreads();

    const int b = i0 >> 12, n0 = i0 & (NTOK - 1);
    float ps = 0.f, pt = 0.f;
    #pragma unroll
    for (int ui = 0; ui < 16; ++ui) {
        int u = quad * 16 + ui;
        float x = Xl[wave][col][u];
        ps = fmaf(x, a1[u], ps);
        pt = fmaf(x, a2[u], pt);
    }
    ps += __shfl_xor(ps, 16, 64); ps += __shfl_xor(ps, 32, 64);
    pt += __shfl_xor(pt, 16, 64); pt += __shfl_xor(pt, 32, 64);
    const float LOG2E = 1.44269504f;
    if (quad == 0) s_out[i0 + col] = ps * LOG2E;   // exp2 domain
    if (quad == 1) t_out[i0 + col] = pt * LOG2E;

    #pragma unroll
    for (int ui = 0; ui < 16; ++ui) {
        int u = quad * 16 + ui;
        XT[(size_t)(b * UDIM + u) * NTOK + n0 + col] = f2bf(Xl[wave][col][u]);
    }
}

// ---------------- kernel 2: fused mask+softmax+PV ---------------------------
// grid 512 = 8 batches x 64 row-tiles-of-64 (b = bx&7), 4 waves/block.
// Each wave: 4 row-groups of 16 x its K-chunk of 1024, step 32.
// B-frags / t loads shared across the 4 row-groups (4x XT traffic cut).
__global__ __launch_bounds__(256) void attn_kernel(
    const float* __restrict__ A,            // f32 [B, N, N] -- 512 MB stream
    const unsigned short* __restrict__ XT,  // bf16 [B, 64, N]
    const float* __restrict__ s_in,         // log2e-scaled
    const float* __restrict__ t_in,         // log2e-scaled
    float* __restrict__ out)                // f32 [B, N, 64]
{
    __shared__ float part[4][64][UDIM + 1]; // 66.6 KB: per-wave partial numerators
    __shared__ float denl[4][64];

    const int tid  = threadIdx.x;
    const int wave = tid >> 6, lane = tid & 63;
    const int bx   = blockIdx.x;
    const int b    = bx & 7;
    const int i0   = (bx >> 3) * 64;
    const int col  = lane & 15, quad = lane >> 4;
    const int kstart = wave * (NTOK / 4);

    float s_m[4];
    #pragma unroll
    for (int g = 0; g < 4; ++g) s_m[g] = s_in[b * NTOK + i0 + g * 16 + col];

    const float* ap[4];
    #pragma unroll
    for (int g = 0; g < 4; ++g)
        ap[g] = A + ((size_t)(b * NTOK + i0 + g * 16 + col)) * NTOK + kstart + quad * 8;
    const float* tptr = t_in + b * NTOK + kstart + quad * 8;
    const unsigned short* xb  = XT + (size_t)b * UDIM * NTOK + kstart + quad * 8;
    const unsigned short* xp0 = xb + (size_t)(col)      * NTOK;
    const unsigned short* xp1 = xb + (size_t)(16 + col) * NTOK;
    const unsigned short* xp2 = xb + (size_t)(32 + col) * NTOK;
    const unsigned short* xp3 = xb + (size_t)(48 + col) * NTOK;

    f32x4 acc[4][4];
    #pragma unroll
    for (int g = 0; g < 4; ++g)
        #pragma unroll
        for (int f = 0; f < 4; ++f) acc[g][f] = (f32x4){0,0,0,0};
    float den[4] = {0.f, 0.f, 0.f, 0.f};

    #pragma unroll 2
    for (int step = 0; step < 32; ++step) {
        short8 bf0 = *(const short8*)xp0;          // shared across row-groups
        short8 bf1 = *(const short8*)xp1;
        short8 bf2 = *(const short8*)xp2;
        short8 bf3 = *(const short8*)xp3;
        f32x4 t0  = *(const f32x4*)tptr;           // k = quad*8 + 0..3
        f32x4 t1  = *(const f32x4*)(tptr + 4);     // k = quad*8 + 4..7

        #pragma unroll
        for (int g = 0; g < 4; ++g) {
            f32x4 am0 = __builtin_nontemporal_load((const f32x4*)ap[g]);
            f32x4 am1 = __builtin_nontemporal_load((const f32x4*)(ap[g] + 4));
            unsigned uw[8];
            #pragma unroll
            for (int j = 0; j < 4; ++j) {
                float l0 = s_m[g] + t0[j], l1 = s_m[g] + t1[j];
                float e0 = fmaxf(l0, 0.2f * l0);   // lrelu commutes with log2e>0
                float e1 = fmaxf(l1, 0.2f * l1);
                float w0 = __builtin_amdgcn_exp2f(e0) * am0[j];  // masked -> exact 0
                float w1 = __builtin_amdgcn_exp2f(e1) * am1[j];
                den[g] += w0 + w1;
                uw[j]     = __float_as_uint(w0) + 0x8000u;  // round-half-up bf16
                uw[4 + j] = __float_as_uint(w1) + 0x8000u;
            }
            PackU p;   // pack hi16 pairs: afr[k]=w(k), k=quad*8+j
            p.u[0] = __builtin_amdgcn_perm(uw[1], uw[0], 0x07060302u);
            p.u[1] = __builtin_amdgcn_perm(uw[3], uw[2], 0x07060302u);
            p.u[2] = __builtin_amdgcn_perm(uw[5], uw[4], 0x07060302u);
            p.u[3] = __builtin_amdgcn_perm(uw[7], uw[6], 0x07060302u);

            acc[g][0] = __builtin_amdgcn_mfma_f32_16x16x32_bf16(p.s, bf0, acc[g][0], 0, 0, 0);
            acc[g][1] = __builtin_amdgcn_mfma_f32_16x16x32_bf16(p.s, bf1, acc[g][1], 0, 0, 0);
            acc[g][2] = __builtin_amdgcn_mfma_f32_16x16x32_bf16(p.s, bf2, acc[g][2], 0, 0, 0);
            acc[g][3] = __builtin_amdgcn_mfma_f32_16x16x32_bf16(p.s, bf3, acc[g][3], 0, 0, 0);
            ap[g] += 32;
        }
        tptr += 32; xp0 += 32; xp1 += 32; xp2 += 32; xp3 += 32;
    }

    #pragma unroll
    for (int g = 0; g < 4; ++g) {
        den[g] += __shfl_xor(den[g], 16, 64);
        den[g] += __shfl_xor(den[g], 32, 64);
        if (quad == 0) denl[wave][g * 16 + col] = den[g];
        #pragma unroll
        for (int r = 0; r < 4; ++r) {
            part[wave][g * 16 + quad * 4 + r][col]      = acc[g][0][r];
            part[wave][g * 16 + quad * 4 + r][16 + col] = acc[g][1][r];
            part[wave][g * 16 + quad * 4 + r][32 + col] = acc[g][2][r];
            part[wave][g * 16 + quad * 4 + r][48 + col] = acc[g][3][r];
        }
    }
    __syncthreads();

    // cross-wave reduce + divide + relu + store (64 rows x 64 u, coalesced)
    #pragma unroll
    for (int rep = 0; rep < 16; ++rep) {
        int e = rep * 256 + tid;
        int r = e >> 6, u = e & 63;
        float num = part[0][r][u] + part[1][r][u] + part[2][r][u] + part[3][r][u];
        float dd  = denl[0][r] + denl[1][r] + denl[2][r] + denl[3][r];
        float o   = fmaxf(num / dd, 0.f);
        __builtin_nontemporal_store(o, &out[(size_t)(b * NTOK + i0 + r) * UDIM + u]);
    }
}

extern "C" void kernel_launch(void* const* d_in, const int* in_sizes, int n_in,
                              void* d_out, int out_size, void* d_ws, size_t ws_size,
                              hipStream_t stream) {
    const float* H  = (const float*)d_in[0];
    const float* A  = (const float*)d_in[1];
    const float* W  = (const float*)d_in[2];
    const float* a1 = (const float*)d_in[3];
    const float* a2 = (const float*)d_in[4];
    float* out = (float*)d_out;

    char* ws = (char*)d_ws;
    unsigned short* XT = (unsigned short*)ws;                               // 4 MB bf16
    float* s = (float*)(ws + (size_t)BATCH * UDIM * NTOK * 2);              // 128 KB
    float* t = (float*)(ws + (size_t)BATCH * UDIM * NTOK * 2 + (size_t)BATCH * NTOK * 4);

    prep_kernel<<<512, 256, 0, stream>>>(H, W, a1, a2, XT, s, t);
    attn_kernel<<<512, 256, 0, stream>>>(A, XT, s, t, out);
}